// Round 2
// baseline (673.631 us; speedup 1.0000x reference)
//
#include <hip/hip_runtime.h>

// VQ-VAE vector-quantize, fused: distances + argmin + gather + loss.
// x: [65536, 256] fp32, dict: [256, 1024] fp32.
// out: q_ste [65536*256] fp32, then loss scalar at out[65536*256].
//
// NUMERICS: the harness checks against a numpy fp32 reference that computes
//   dist = fl( fl(||f||^2 + ||e||^2) - fl(2*s) )  with ||f||^2 ~ 256,
// i.e. distances quantized at ulp(256)~3e-5; ~10 rows of 65536 are exact fp32
// ties resolved by first-index. We must EMULATE that arithmetic (numpy pairwise
// sum for ||f||^2, unfused squares, same final rounding), not exceed it.

#define NROWS 65536
#define DDIM  256
#define KC    1024
#define BM    64      // rows per block
#define BC    128     // codes per tile
#define DC    32      // d-chunk for dict staging
#define NCT   (KC / BC)    // 8 code tiles
#define NDC   (DDIM / DC)  // 8 d chunks

// Pre-kernel: codebook column norms (np order: rounded square, then plain add,
// sequential d ascending) + transposed codebook for the epilogue gather.
__global__ __launch_bounds__(256) void vq_prep(const float* __restrict__ dict,
                                               float* __restrict__ enorm,
                                               float* __restrict__ dictT) {
#pragma clang fp contract(off)
    int k = blockIdx.x * 256 + threadIdx.x;   // code index, coalesced over d-rows
    float s = 0.f;
    for (int d = 0; d < DDIM; ++d) {
        float v = dict[(size_t)d * KC + k];
        float sq = v * v;          // rounded square (np temp array)
        s = s + sq;                // plain add, NOT fma
        dictT[(size_t)k * DDIM + d] = v;
    }
    enorm[k] = s;
}

__global__ __launch_bounds__(256, 2) void vq_main(const float* __restrict__ x,
                                                  const float* __restrict__ dict,
                                                  const float* __restrict__ enorm,
                                                  const float* __restrict__ dictT,
                                                  float* __restrict__ out,
                                                  float* __restrict__ loss) {
    // fT: x tile transposed [d][row] (64 KB). dT: dict tile [d-chunk][code] (16 KB).
    // Total exactly 80 KB -> 2 blocks/CU (160 KB LDS). dT doubles as scratch for
    // the per-row ||f||^2 staging and the final index broadcast.
    __shared__ float fT[DDIM][BM];
    __shared__ float dT[DC][BC];

    const int tid = threadIdx.x;
    const int tx  = tid & 15;   // codes dim (16 threads x 8 codes = 128)
    const int ty  = tid >> 4;   // rows dim  (16 threads x 4 rows  = 64)
    const int rowbase = blockIdx.x * BM;

    // Stage x tile: thread = d index, iterate rows.
    for (int i = 0; i < BM; ++i)
        fT[tid][i] = x[(size_t)(rowbase + i) * DDIM + tid];
    __syncthreads();

    // ||f||^2 per row, replicating numpy pairwise_sum for n=256:
    // split 128+128; each leaf = 8 accumulators, 15 unrolled-8 iterations,
    // combine ((r0+r1)+(r2+r3))+((r4+r5)+(r6+r7)). Unfused squares.
    if (tid < BM) {
        float total;
        {
#pragma clang fp contract(off)
            float half[2];
            for (int h = 0; h < 2; ++h) {
                const int d0 = h * 128;
                float r8[8];
                #pragma unroll
                for (int j = 0; j < 8; ++j) {
                    float v = fT[d0 + j][tid];
                    r8[j] = v * v;
                }
                for (int i = 8; i < 128; i += 8)
                    #pragma unroll
                    for (int j = 0; j < 8; ++j) {
                        float v = fT[d0 + i + j][tid];
                        float sq = v * v;
                        r8[j] = r8[j] + sq;
                    }
                half[h] = ((r8[0] + r8[1]) + (r8[2] + r8[3]))
                        + ((r8[4] + r8[5]) + (r8[6] + r8[7]));
            }
            total = half[0] + half[1];
        }
        ((float*)dT)[tid] = total;
    }
    __syncthreads();
    float Arow[4];
    #pragma unroll
    for (int r = 0; r < 4; ++r) Arow[r] = ((float*)dT)[ty * 4 + r];
    // (next __syncthreads below separates this read from dT overwrite)

    float minv[4] = {3.4e38f, 3.4e38f, 3.4e38f, 3.4e38f};
    int   mini[4] = {0, 0, 0, 0};

    for (int ct = 0; ct < NCT; ++ct) {
        const int cbase = ct * BC;
        float acc[4][8];
        #pragma unroll
        for (int r = 0; r < 4; ++r)
            #pragma unroll
            for (int j = 0; j < 8; ++j) acc[r][j] = 0.f;

        for (int dc = 0; dc < NDC; ++dc) {
            __syncthreads();
            // Load dict tile [DC x BC]: 16 floats/thread, coalesced over codes.
            #pragma unroll
            for (int i = 0; i < (DC * BC) / 256; ++i) {
                int idx = i * 256 + tid;
                int dd = idx >> 7;        // / BC
                int cc = idx & (BC - 1);
                dT[dd][cc] = dict[(size_t)(dc * DC + dd) * KC + cbase + cc];
            }
            __syncthreads();
            const int dbase = dc * DC;
            #pragma unroll
            for (int dd = 0; dd < DC; ++dd) {
                // rows: broadcast across tx (free); codes: 16B-stride, conflict-free
                const float4 fv = *(const float4*)(&fT[dbase + dd][ty * 4]);
                const float4 ea = *(const float4*)(&dT[dd][tx * 4]);
                const float4 eb = *(const float4*)(&dT[dd][64 + tx * 4]);
                const float fr[4] = {fv.x, fv.y, fv.z, fv.w};
                const float ec[8] = {ea.x, ea.y, ea.z, ea.w, eb.x, eb.y, eb.z, eb.w};
                #pragma unroll
                for (int r = 0; r < 4; ++r)
                    #pragma unroll
                    for (int j = 0; j < 8; ++j)
                        acc[r][j] = fmaf(fr[r], ec[j], acc[r][j]);
            }
        }

        // dist = fl( fl(A + B) - 2*s )  — exactly the np rounding chain.
        // (fma contraction of t1 - 2*acc is bit-identical since 2*acc is exact.)
        // Codes ascend with (ct, j) -> strict < keeps FIRST min index, like np.argmin.
        float en[8];
        #pragma unroll
        for (int j = 0; j < 8; ++j) {
            int code = cbase + ((j < 4) ? (tx * 4 + j) : (64 + tx * 4 + (j - 4)));
            en[j] = enorm[code];
        }
        #pragma unroll
        for (int r = 0; r < 4; ++r)
            #pragma unroll
            for (int j = 0; j < 8; ++j) {
                int code = cbase + ((j < 4) ? (tx * 4 + j) : (64 + tx * 4 + (j - 4)));
                float t1 = Arow[r] + en[j];
                float dist = t1 - 2.0f * acc[r][j];
                if (dist < minv[r]) { minv[r] = dist; mini[r] = code; }
            }
    }

    // Cross-lane argmin over the 16 tx lanes (xor masks stay inside the wave:
    // lane = (ty&3)*16 + tx). Tie -> smaller index, matching first-occurrence.
    #pragma unroll
    for (int m = 1; m < 16; m <<= 1)
        #pragma unroll
        for (int r = 0; r < 4; ++r) {
            float ov = __shfl_xor(minv[r], m, 64);
            int   oi = __shfl_xor(mini[r], m, 64);
            if (ov < minv[r] || (ov == minv[r] && oi < mini[r])) {
                minv[r] = ov; mini[r] = oi;
            }
        }

    __syncthreads();                 // dT no longer needed: alias as idx store
    int* idx_s = (int*)&dT[0][0];
    if (tx == 0) {
        #pragma unroll
        for (int r = 0; r < 4; ++r) idx_s[ty * 4 + r] = mini[r];
    }
    __syncthreads();

    // Epilogue: gather codebook row (coalesced from dictT, L2-resident 1 MB),
    // emulate straight-through q_ste = fl(x + fl(q - x)), accumulate loss on
    // the PURE gathered q (reference computes loss before the STE line).
    float lsum = 0.f;
    {
#pragma clang fp contract(off)
        for (int i = 0; i < BM; ++i) {
            int k = idx_s[i];
            float qv = dictT[(size_t)k * DDIM + tid];
            float xv = fT[tid][i];
            float diff = qv - xv;                       // fl(q - x)
            out[(size_t)(rowbase + i) * DDIM + tid] = xv + diff;  // fl(x + fl(q-x))
            float d = xv - qv;
            float dsq = d * d;
            lsum = lsum + dsq;
        }
    }
    #pragma unroll
    for (int off = 32; off > 0; off >>= 1)
        lsum += __shfl_down(lsum, off, 64);
    if ((tid & 63) == 0)
        atomicAdd(loss, lsum * (1.25f / 16777216.0f));  // (1+BETA)/(N*D)
}

extern "C" void kernel_launch(void* const* d_in, const int* in_sizes, int n_in,
                              void* d_out, int out_size, void* d_ws, size_t ws_size,
                              hipStream_t stream) {
    (void)in_sizes; (void)n_in; (void)out_size; (void)ws_size;
    const float* x    = (const float*)d_in[0];
    const float* dict = (const float*)d_in[1];
    float* out   = (float*)d_out;
    float* enorm = (float*)d_ws;                 // 1024 floats
    float* dictT = enorm + KC;                   // 1024*256 floats (1 MB)
    float* loss  = out + (size_t)NROWS * DDIM;   // scalar slot after q

    hipMemsetAsync(loss, 0, sizeof(float), stream);  // d_ws/d_out are poisoned 0xAA
    vq_prep<<<KC / 256, 256, 0, stream>>>(dict, enorm, dictT);
    vq_main<<<NROWS / BM, 256, 0, stream>>>(x, dict, enorm, dictT, out, loss);
}

// Round 3
// 617.316 us; speedup vs baseline: 1.0912x; 1.0912x over previous
//
#include <hip/hip_runtime.h>

// VQ-VAE vector-quantize, fused: distances + argmin + gather + loss.
// x: [65536, 256] fp32, dict: [256, 1024] fp32.
// out: q_ste [65536*256] fp32, then loss scalar at out[65536*256].
//
// NUMERICS (bit-exact vs np reference, verified absmax 0.0 in R2 — DO NOT CHANGE):
//  - row norm ||f||^2: np pairwise tree (two 128-halves, 8 accumulators,
//    unfused squares, fixed combine tree)
//  - enorm ||e||^2: sequential d ascending, unfused square then plain add
//  - dist = fl( fl(A + B) - 2*s ), argmin first-index on exact ties
//  - STE out = fl(x + fl(q - x)); loss on pure q, (1+BETA)/(N*D) scale
//
// PERF (R2 -> R3): R2 was LDS-read-throughput bound (3 ds_read_b128 per 32
// FMAs; 8 waves/CU x 36 LDS-cyc vs 128 FMA-cyc/SIMD = 2.25x). R3 enlarges the
// register tile to 8 rows x 16 codes (128 acc VGPRs): 6 ds_read_b128 per 128
// FMAs. BM=128 rows forces streaming x tiles (L3-resident re-reads, ~free).

#define NROWS 65536
#define DDIM  256
#define KC    1024
#define BM    128     // rows per block
#define BC    256     // codes per ct tile
#define DC    32      // d-chunk per staging step
#define NCT   (KC / BC)     // 4
#define NDC   (DDIM / DC)   // 8
#define FXPITCH 132   // padded row pitch for fX: breaks stride-128 bank aliasing

// Pre-kernel: codebook column norms (np order: rounded square, then plain add,
// sequential d ascending) + transposed codebook for the epilogue gather.
__global__ __launch_bounds__(256) void vq_prep(const float* __restrict__ dict,
                                               float* __restrict__ enorm,
                                               float* __restrict__ dictT) {
#pragma clang fp contract(off)
    int k = blockIdx.x * 256 + threadIdx.x;
    float s = 0.f;
    for (int d = 0; d < DDIM; ++d) {
        float v = dict[(size_t)d * KC + k];
        float sq = v * v;          // rounded square (np temp array)
        s = s + sq;                // plain add, NOT fma
        dictT[(size_t)k * DDIM + d] = v;
    }
    enorm[k] = s;
}

__global__ __launch_bounds__(256, 2) void vq_main(const float* __restrict__ x,
                                                  const float* __restrict__ dict,
                                                  const float* __restrict__ enorm,
                                                  const float* __restrict__ dictT,
                                                  float* __restrict__ out,
                                                  float* __restrict__ loss) {
    __shared__ float fX[DC * FXPITCH];   // x tile, transposed [d][row], padded (16.9 KB)
    __shared__ float dTs[DC * BC];       // dict tile [d][code] (32 KB)
    __shared__ float rnormS[BM];         // per-row ||f||^2

    const int tid = threadIdx.x;
    const int tx  = tid & 15;            // 16 code-groups x 16 codes = 256
    const int ty  = tid >> 4;            // 16 row-groups  x  8 rows  = 128
    const int rowbase = blockIdx.x * BM;

    // Stage fX for d-range [d0, d0+32): float4 global loads (coalesced), scalar
    // transposed LDS stores. Pitch 132 => bank = (4*dd + row) % 32: 16 banks,
    // 4 words/bank per store inst (vs 64-on-1 unpadded).
    auto stage_fx = [&](int d0) {
        #pragma unroll
        for (int i = 0; i < 4; ++i) {
            int flat4 = i * 256 + tid;           // 0..1023
            int row   = flat4 >> 3;              // 0..127
            int c4    = flat4 & 7;               // 0..7 (d-quad)
            const float4 v = *(const float4*)&x[(size_t)(rowbase + row) * DDIM + d0 + c4 * 4];
            fX[(c4 * 4 + 0) * FXPITCH + row] = v.x;
            fX[(c4 * 4 + 1) * FXPITCH + row] = v.y;
            fX[(c4 * 4 + 2) * FXPITCH + row] = v.z;
            fX[(c4 * 4 + 3) * FXPITCH + row] = v.w;
        }
    };

    // ---- Phase N: row norms, np pairwise (bit-exact R2 tree; r8 starts at 0,
    // 0 + sq == sq exactly, so identical to init-from-first-chunk).
    float halfv[2] = {0.f, 0.f};
    for (int h = 0; h < 2; ++h) {
        float r8[8] = {0.f, 0.f, 0.f, 0.f, 0.f, 0.f, 0.f, 0.f};
        for (int c = 0; c < 4; ++c) {
            __syncthreads();
            stage_fx(h * 128 + c * 32);
            __syncthreads();
            if (tid < BM) {
#pragma clang fp contract(off)
                #pragma unroll
                for (int i = 0; i < 4; ++i)
                    #pragma unroll
                    for (int j = 0; j < 8; ++j) {
                        float v  = fX[(i * 8 + j) * FXPITCH + tid];
                        float sq = v * v;
                        r8[j] = r8[j] + sq;
                    }
            }
        }
        if (tid < BM)
            halfv[h] = ((r8[0] + r8[1]) + (r8[2] + r8[3]))
                     + ((r8[4] + r8[5]) + (r8[6] + r8[7]));
    }
    if (tid < BM) rnormS[tid] = halfv[0] + halfv[1];
    __syncthreads();

    float Arow[8];
    #pragma unroll
    for (int r = 0; r < 8; ++r) Arow[r] = rnormS[ty * 8 + r];

    float minv[8];
    int   mini[8];
    #pragma unroll
    for (int r = 0; r < 8; ++r) { minv[r] = 3.4e38f; mini[r] = 0; }

    // ---- Main: 4 code-tiles x 8 d-chunks; per dd: 6 ds_read_b128, 128 FMAs.
    for (int ct = 0; ct < NCT; ++ct) {
        const int cbase = ct * BC;
        float acc[8][16];
        #pragma unroll
        for (int r = 0; r < 8; ++r)
            #pragma unroll
            for (int j = 0; j < 16; ++j) acc[r][j] = 0.f;

        for (int dc = 0; dc < NDC; ++dc) {
            __syncthreads();
            stage_fx(dc * DC);
            // dict tile [32][256]: float4 loads + float4 LDS stores, conflict-free.
            #pragma unroll
            for (int i = 0; i < 8; ++i) {
                int flat4 = i * 256 + tid;       // 0..2047
                int dd = flat4 >> 6;             // 0..31
                int c4 = (flat4 & 63) * 4;       // 0..252
                *(float4*)&dTs[dd * BC + c4] =
                    *(const float4*)&dict[(size_t)(dc * DC + dd) * KC + cbase + c4];
            }
            __syncthreads();
            #pragma unroll 8
            for (int dd = 0; dd < DC; ++dd) {
                const float4 f0 = *(const float4*)&fX[dd * FXPITCH + ty * 8];
                const float4 f1 = *(const float4*)&fX[dd * FXPITCH + ty * 8 + 4];
                const float4 e0 = *(const float4*)&dTs[dd * BC + tx * 4];
                const float4 e1 = *(const float4*)&dTs[dd * BC + 64 + tx * 4];
                const float4 e2 = *(const float4*)&dTs[dd * BC + 128 + tx * 4];
                const float4 e3 = *(const float4*)&dTs[dd * BC + 192 + tx * 4];
                const float fr[8]  = {f0.x, f0.y, f0.z, f0.w, f1.x, f1.y, f1.z, f1.w};
                const float ec[16] = {e0.x, e0.y, e0.z, e0.w, e1.x, e1.y, e1.z, e1.w,
                                      e2.x, e2.y, e2.z, e2.w, e3.x, e3.y, e3.z, e3.w};
                #pragma unroll
                for (int r = 0; r < 8; ++r)
                    #pragma unroll
                    for (int j = 0; j < 16; ++j)
                        acc[r][j] = fmaf(fr[r], ec[j], acc[r][j]);
            }
        }

        // dist = fl( fl(A + B) - 2*s ) — np rounding chain (fma of t1 - 2*acc is
        // bit-identical: 2*acc exact). Codes ascend with (ct, j) for fixed tx ->
        // strict < keeps FIRST min index, like np.argmin.
        float en[16];
        #pragma unroll
        for (int j = 0; j < 16; ++j)
            en[j] = enorm[cbase + (j >> 2) * 64 + tx * 4 + (j & 3)];
        #pragma unroll
        for (int r = 0; r < 8; ++r)
            #pragma unroll
            for (int j = 0; j < 16; ++j) {
                int code = cbase + (j >> 2) * 64 + tx * 4 + (j & 3);
                float t1 = Arow[r] + en[j];
                float dist = t1 - 2.0f * acc[r][j];
                if (dist < minv[r]) { minv[r] = dist; mini[r] = code; }
            }
    }

    // Cross-lane argmin over the 16 tx lanes (xor<16 stays in-wave; lane =
    // (ty&3)*16 + tx). Tie -> smaller index (first occurrence).
    #pragma unroll
    for (int m = 1; m < 16; m <<= 1)
        #pragma unroll
        for (int r = 0; r < 8; ++r) {
            float ov = __shfl_xor(minv[r], m, 64);
            int   oi = __shfl_xor(mini[r], m, 64);
            if (ov < minv[r] || (ov == minv[r] && oi < mini[r])) {
                minv[r] = ov; mini[r] = oi;
            }
        }

    __syncthreads();                 // dTs no longer needed: alias as idx store
    int* idx_s = (int*)dTs;
    if (tx == 0) {
        #pragma unroll
        for (int r = 0; r < 8; ++r) idx_s[ty * 8 + r] = mini[r];
    }
    __syncthreads();

    // Epilogue: gather codebook row (dictT L2-resident), re-read x (L3-hot),
    // emulate STE out = fl(x + fl(q-x)), loss on pure q (before STE).
    float lsum = 0.f;
    {
#pragma clang fp contract(off)
        for (int i = 0; i < BM; ++i) {
            int k = idx_s[i];
            float qv = dictT[(size_t)k * DDIM + tid];
            float xv = x[(size_t)(rowbase + i) * DDIM + tid];
            float diff = qv - xv;                                 // fl(q - x)
            out[(size_t)(rowbase + i) * DDIM + tid] = xv + diff;  // fl(x + fl(q-x))
            float d = xv - qv;
            float dsq = d * d;
            lsum = lsum + dsq;
        }
    }
    #pragma unroll
    for (int off = 32; off > 0; off >>= 1)
        lsum += __shfl_down(lsum, off, 64);
    if ((tid & 63) == 0)
        atomicAdd(loss, lsum * (1.25f / 16777216.0f));  // (1+BETA)/(N*D)
}

extern "C" void kernel_launch(void* const* d_in, const int* in_sizes, int n_in,
                              void* d_out, int out_size, void* d_ws, size_t ws_size,
                              hipStream_t stream) {
    (void)in_sizes; (void)n_in; (void)out_size; (void)ws_size;
    const float* x    = (const float*)d_in[0];
    const float* dict = (const float*)d_in[1];
    float* out   = (float*)d_out;
    float* enorm = (float*)d_ws;                 // 1024 floats
    float* dictT = enorm + KC;                   // 1024*256 floats (1 MB)
    float* loss  = out + (size_t)NROWS * DDIM;   // scalar slot after q

    hipMemsetAsync(loss, 0, sizeof(float), stream);  // d_ws/d_out are poisoned 0xAA
    vq_prep<<<KC / 256, 256, 0, stream>>>(dict, enorm, dictT);
    vq_main<<<NROWS / BM, 256, 0, stream>>>(x, dict, enorm, dictT, out, loss);
}